// Round 5
// baseline (2698.917 us; speedup 1.0000x reference)
//
#include <hip/hip_runtime.h>

#define B 8
#define N 8192
#define S 2048
#define K 32
#define TPB 512          // FPS threads/block (8 waves)
#define PPT (N / TPB)    // 16 contiguous points per thread: gid = t*16 + i

// Exact (no-FMA, left-to-right) squared distance to match numpy/XLA fp32:
// ((dx*dx + dy*dy) + dz*dz). FPS argmax is a chaotic recurrence; any ulp
// difference can diverge the selected-center sequence. Verified absmax==0 (R1-R4).
__device__ __forceinline__ float sqdist3(float ax, float ay, float az,
                                         float bx, float by, float bz) {
    float dx = ax - bx, dy = ay - by, dz = az - bz;
    return __fadd_rn(__fadd_rn(__fmul_rn(dx, dx), __fmul_rn(dy, dy)),
                     __fmul_rn(dz, dz));
}

// DPP max: VALU-latency cross-lane (vs ds_bpermute-based __shfl ~LDS latency).
template <int CTRL>
__device__ __forceinline__ float dpp_fmax(float v) {
    const int iv = __float_as_int(v);
    const int sh = __builtin_amdgcn_update_dpp(iv, iv, CTRL, 0xF, 0xF, false);
    return fmaxf(v, __int_as_float(sh));
}

// Full-wave (64 lane) max via DPP; result broadcast from lane 63.
__device__ __forceinline__ float wave_fmax_dpp(float v) {
    v = dpp_fmax<0x111>(v);  // row_shr:1
    v = dpp_fmax<0x112>(v);  // row_shr:2
    v = dpp_fmax<0x114>(v);  // row_shr:4
    v = dpp_fmax<0x118>(v);  // row_shr:8
    v = dpp_fmax<0x142>(v);  // row_bcast:15
    v = dpp_fmax<0x143>(v);  // row_bcast:31 -> lane 63 = wave max
    return __int_as_float(__builtin_amdgcn_readlane(__float_as_int(v), 63));
}

// ---------------------------------------------------------------------------
// FPS: one block per batch, 512 threads, 16 CONTIGUOUS points/thread in regs.
// R5 key change: __launch_bounds__(512, 2). R4's default budget allocated only
// 68 VGPRs -> x/y/z/md[16] were demoted to AGPRs, adding v_accvgpr_read/write
// on every hot-loop array access (~2x issue inflation; VALUBusy showed ~82%
// busy on active CUs => issue-bound). 2 waves/EU is this kernel's actual
// occupancy (8 waves / 4 SIMDs, 1 block/CU), raising the VGPR cap to 256.
// Structure otherwise as R4: zero global ops in loop, one barrier/step,
// single float4 publish per wave, DPP wave-max + ballot tie-break.
// Selection order identical to R1-R4: (max dist, then lowest gid).
// ---------------------------------------------------------------------------
__global__ __launch_bounds__(TPB, 2) void fps_kernel(const float* __restrict__ xyz,
                                                     float* __restrict__ centers) {
    const int b = blockIdx.x;
    const float* xb = xyz + (size_t)b * N * 3;
    const int t = threadIdx.x;

    // load 16 contiguous points (48 floats = 12 float4, 16B-aligned: 192B*t)
    float raw[3 * PPT];
    const float4* src = (const float4*)(xb + 3 * PPT * t);
#pragma unroll
    for (int i = 0; i < 3 * PPT / 4; ++i) {
        const float4 v = src[i];
        raw[4 * i + 0] = v.x; raw[4 * i + 1] = v.y;
        raw[4 * i + 2] = v.z; raw[4 * i + 3] = v.w;
    }
    float x[PPT], y[PPT], z[PPT], md[PPT];
#pragma unroll
    for (int i = 0; i < PPT; ++i) {
        x[i] = raw[3 * i + 0];
        y[i] = raw[3 * i + 1];
        z[i] = raw[3 * i + 2];
        md[i] = INFINITY;
    }

    __shared__ float4 pub[2][8];        // per-wave {wmax, x, y, z}, dbuf
    __shared__ float cent[S * 3];       // centers staged in LDS (24 KB)

    // step 0: reference always picks point 0
    float px = xb[0], py = xb[1], pz = xb[2];
    if (t == 0) { cent[0] = px; cent[1] = py; cent[2] = pz; }

    const int wid = t >> 6;
    const int lane = t & 63;
    for (int s = 1; s < S; ++s) {
        // --- local update; best = tree max (log-depth, no index tracking)
        float m[PPT];
#pragma unroll
        for (int i = 0; i < PPT; ++i) {
            const float d = sqdist3(x[i], y[i], z[i], px, py, pz);
            m[i] = fminf(md[i], d);
            md[i] = m[i];
        }
#pragma unroll
        for (int st = 1; st < PPT; st <<= 1)
#pragma unroll
            for (int i = 0; i < PPT; i += 2 * st)
                m[i] = fmaxf(m[i], m[i + st]);
        const float best = m[0];

        // --- wave max (DPP) + first-lane tie-break via ballot
        const float wmax = wave_fmax_dpp(best);
        const unsigned long long mb = __ballot(best == wmax);
        const int ol = (int)__builtin_ctzll(mb);   // lowest lane == lowest gid

        // --- wave owner: re-derive bi (descending overwrite -> lowest i),
        //     publish {wmax, coords} as one b128 write (execz-skipped branch)
        const int pb = s & 1;
        if (lane == ol) {
            int bi = 0;
#pragma unroll
            for (int i = PPT - 1; i >= 0; --i)
                if (md[i] == wmax) bi = i;
            pub[pb][wid] = make_float4(wmax, x[bi], y[bi], z[bi]);
        }
        __syncthreads();                           // the ONLY barrier per step

        // --- scan 8 wave winners (independent broadcast b128 reads)
        float4 v0 = pub[pb][0];
        float gmax = v0.x;
        px = v0.y; py = v0.z; pz = v0.w;
#pragma unroll
        for (int w = 1; w < 8; ++w) {
            const float4 u = pub[pb][w];
            const bool g = u.x > gmax;             // strict: lowest wid wins ties
            gmax = g ? u.x : gmax;
            px = g ? u.y : px;
            py = g ? u.z : py;
            pz = g ? u.w : pz;
        }

        // --- winner coords already in every thread's registers; t0 stages them
        if (t == 0) {
            cent[3 * s + 0] = px;
            cent[3 * s + 1] = py;
            cent[3 * s + 2] = pz;
        }
    }

    // --- coalesced dump of centers LDS -> global (S*3 = 6144 = 512*12)
    __syncthreads();
    float* cb = centers + (size_t)b * S * 3;
#pragma unroll
    for (int j = 0; j < (S * 3) / TPB; ++j) {
        const int idx = t + TPB * j;
        cb[idx] = cent[idx];
    }
}

// ---------------------------------------------------------------------------
// KNN + gather: one wave per center. Top-32 held SORTED across lanes 0..31 as
// packed u64 (dist_bits<<32 | idx) -> lexicographic (d, idx) order == stable
// top_k tie semantics. Insert = wave-wide shfl_up shift (O(1) per insert).
// ---------------------------------------------------------------------------
__global__ __launch_bounds__(256) void knn_kernel(const float* __restrict__ xyz,
                                                  const float* __restrict__ centers,
                                                  float* __restrict__ out) {
    const int gw = (int)((blockIdx.x * blockDim.x + threadIdx.x) >> 6);
    const int lane = (int)(threadIdx.x & 63);
    const int b = gw >> 11;        // gw / S
    const int s = gw & (S - 1);
    const float* xb = xyz + (size_t)b * N * 3;
    const float* c = centers + (size_t)(b * S + s) * 3;
    const float cx = c[0], cy = c[1], cz = c[2];

    unsigned long long P = ~0ULL;     // lanes 0..31: sorted top-32 (asc)
    unsigned long long tau = ~0ULL;   // current worst kept = P at lane 31

    for (int i = 0; i < N / 64; ++i) {
        const int p = (i << 6) + lane;
        const float* q = xb + 3 * p;
        const float d = sqdist3(q[0], q[1], q[2], cx, cy, cz);
        const unsigned long long cand =
            ((unsigned long long)__float_as_uint(d) << 32) | (unsigned)p;
        bool alive = cand < tau;
        unsigned long long mask = __ballot(alive);
        while (mask) {
            const int src = __builtin_ctzll(mask);
            const unsigned long long bc = __shfl(cand, src);
            unsigned long long up = __shfl_up(P, 1);
            if (lane == 0) up = bc;
            const bool gt = P > bc;  // strict: bc < tau guarantees lane31 evicts
            const unsigned long long shifted = (up > bc) ? up : bc;
            P = gt ? shifted : P;
            tau = __shfl(P, 31);
            if (lane == src) alive = false;
            alive = alive && (cand < tau);
            mask = __ballot(alive);
        }
    }

    // epilogue: lane k = k-th nearest (ascending d, ties by index = top_k order)
    if (lane < K) {
        const unsigned nidx = (unsigned)P;
        const float* q = xb + 3 * nidx;
        float* o = out + ((size_t)(b * S + s) * K + lane) * 3;
        o[0] = q[0] - cx;
        o[1] = q[1] - cy;
        o[2] = q[2] - cz;
    }
}

extern "C" void kernel_launch(void* const* d_in, const int* in_sizes, int n_in,
                              void* d_out, int out_size, void* d_ws, size_t ws_size,
                              hipStream_t stream) {
    const float* xyz = (const float*)d_in[0];
    float* out = (float*)d_out;                         // neighborhood [B,S,K,3]
    float* centers = out + (size_t)B * S * K * 3;       // centers [B,S,3]

    fps_kernel<<<B, TPB, 0, stream>>>(xyz, centers);
    knn_kernel<<<(B * S) / 4, 256, 0, stream>>>(xyz, centers, out);
}